// Round 6
// baseline (1008.687 us; speedup 1.0000x reference)
//
#include <hip/hip_runtime.h>

// DecoderLSTM R6: unit-partitioned persistent kernel, batched agent exchange.
// 256 blocks = 64 ped-groups x 4 unit-groups. Block: 128 peds x 64 units.
// Weights: 64 KB LDS + 24 short8 VGPRs/lane, loaded ONCE.
// Exchange: relaxed AGENT atomics (8B), partner loads batched into regs
// (single vmcnt drain), own slice kept LDS-local, coalesced stats layout,
// fully relaxed barrier (no release/acquire cache maintenance).

typedef float  f32x4  __attribute__((ext_vector_type(4)));
typedef short  short8 __attribute__((ext_vector_type(8)));
typedef __bf16 bf16x8 __attribute__((ext_vector_type(8)));

#define WS_W     0                         // 640 KB
#define WS_HBUF  (640 * 1024)              // 8 MB: [2][512][8][512] shorts
#define WS_STATS (WS_HBUF + 8388608)       // 1 MB: [2][64][4][128] float4
#define WS_BIAS  (WS_STATS + 1048576)      // 4 KB
#define WS_SCAL  (WS_BIAS + 4096)          // 64 B
#define WS_CTR   (WS_SCAL + 64)            // 64 * 256 B

typedef unsigned long long u64;

__device__ __forceinline__ unsigned short f2bf(float f) {
  unsigned int u = __float_as_uint(f);
  u += 0x7FFFu + ((u >> 16) & 1u);  // RNE
  return (unsigned short)(u >> 16);
}
__device__ __forceinline__ float sigm(float x) {
  return __builtin_amdgcn_rcpf(1.0f + __expf(-x));
}
__device__ __forceinline__ float tanh_(float x) {
  float ax = fabsf(x);
  float t = __expf(-2.0f * ax);
  float r = (1.0f - t) * __builtin_amdgcn_rcpf(1.0f + t);
  return x >= 0.0f ? r : -r;
}
__device__ __forceinline__ f32x4 mfma16(short8 a, short8 b, f32x4 c) {
  return __builtin_amdgcn_mfma_f32_16x16x32_bf16(
      __builtin_bit_cast(bf16x8, a), __builtin_bit_cast(bf16x8, b), c, 0, 0, 0);
}
__device__ __forceinline__ void st_ag(u64* p, u64 v) {
  __hip_atomic_store(p, v, __ATOMIC_RELAXED, __HIP_MEMORY_SCOPE_AGENT);
}
__device__ __forceinline__ u64 ld_ag(const u64* p) {
  return __hip_atomic_load((u64*)p, __ATOMIC_RELAXED, __HIP_MEMORY_SCOPE_AGENT);
}

// ---- Prologue 1: weights -> B-frag bf16, flat ((ug*10+kc)*16+g*4+uw)*512 ----
extern "C" __global__ void shuffle_weights(const float* __restrict__ Wih,
                                           const float* __restrict__ Whh,
                                           unsigned short* __restrict__ ws_w) {
  int t = blockIdx.x * 256 + threadIdx.x;  // 0..40959
  if (t >= 40960) return;
  int l = t & 63;
  int x = t >> 6;
  int uw = x & 3;
  int g = (x >> 2) & 3;
  int y = x >> 4;  // ug*10 + kc
  int kc = y % 10;
  int ug = y / 10;
  int row = g * 256 + ug * 64 + uw * 16 + (l & 15);
  unsigned short* dst = ws_w + (size_t)t * 8;
  if (kc < 2) {
    const float* src = Wih + row * 64 + kc * 32 + (l >> 4) * 8;
#pragma unroll
    for (int j = 0; j < 8; j++) dst[j] = f2bf(src[j]);
  } else {
    const float* src = Whh + row * 256 + (kc - 2) * 32 + (l >> 4) * 8;
#pragma unroll
    for (int j = 0; j < 8; j++) dst[j] = f2bf(src[j]);
  }
}

// ---- Prologue 2: bias, scal, zero padded counters ---------------------------
extern "C" __global__ void prologue2(const float* __restrict__ b_ih,
                                     const float* __restrict__ b_hh,
                                     const float* __restrict__ ln2g,
                                     const float* __restrict__ ln2b,
                                     const float* __restrict__ posW,
                                     float* __restrict__ biasv,
                                     float* __restrict__ scal,
                                     int* __restrict__ ctr) {
  int t = threadIdx.x;  // 256
#pragma unroll
  for (int k2 = 0; k2 < 4; k2++) {
    int n = t * 4 + k2;
    biasv[n] = b_ih[n] + b_hh[n];
  }
  if (t < 64) ctr[t * 64] = 0;
  __shared__ float red[256][4];
  float g = ln2g[t], b = ln2b[t], p0 = posW[t], p1 = posW[256 + t];
  red[t][0] = b * p0;
  red[t][1] = b * p1;
  red[t][2] = g * p0;
  red[t][3] = g * p1;
  __syncthreads();
  for (int s = 128; s > 0; s >>= 1) {
    if (t < s) {
#pragma unroll
      for (int v = 0; v < 4; v++) red[t][v] += red[t + s][v];
    }
    __syncthreads();
  }
  if (t == 0) {
#pragma unroll
    for (int v = 0; v < 4; v++) scal[v] = red[0][v];
  }
}

// ---- Main persistent decoder ------------------------------------------------
extern "C" __global__ __launch_bounds__(512, 2) void decoder_main(
    const float* __restrict__ lpr, const float* __restrict__ h0,
    const float* __restrict__ c0, const float* __restrict__ embW,
    const float* __restrict__ embB, const float* __restrict__ ln1g,
    const float* __restrict__ ln1b, const float* __restrict__ posW,
    const float* __restrict__ posB, const float* __restrict__ ln2g,
    const unsigned short* __restrict__ ws_w,
    unsigned short* __restrict__ hbuf,  // [2][512][8][512] shorts
    float* __restrict__ stats,          // [2][64][4][128] float4
    const float* __restrict__ biasv, const float* __restrict__ scal,
    int* __restrict__ ctr, float* __restrict__ out) {
  __shared__ unsigned short w_lds[4 * 16 * 512];   // 64 KB, kc 0..3
  __shared__ unsigned short h_stage[8 * 8 * 512];  // 64 KB [Tl8][kc8][512]
  __shared__ unsigned short xh[16 * 512];          // 16 KB x-frags / h_out
  __shared__ float partials[128 * 16];             // 8 KB
  __shared__ float n01[128][2];

  const int bid = blockIdx.x;
  const int pg = bid >> 2, ug = bid & 3;
  const int tid = threadIdx.x;
  const int w = tid >> 6, l = tid & 63;
  const int uw = w & 3, pw = w >> 2;
  const int q = l >> 4, li = l & 15;
  const int P0 = pg * 128;
  const int loff = l * 8;
  const int u = ug * 64 + uw * 16 + li;

  // ---- weights: LDS part (kc 0..3) ----
  {
    const unsigned short* src = ws_w + (size_t)ug * 81920;
#pragma unroll
    for (int it = 0; it < 8; it++) {
      int f = tid + it * 512;
      *(short8*)(w_lds + f * 8) = *(const short8*)(src + f * 8);
    }
  }
  // ---- weights: register part (kc 4..9) ----
  short8 wr[6][4];
#pragma unroll
  for (int kk = 0; kk < 6; kk++)
#pragma unroll
    for (int g = 0; g < 4; g++)
      wr[kk][g] = *(const short8*)(ws_w + (size_t)ug * 81920 +
                                   ((kk + 4) * 16 + g * 4 + uw) * 512 + loff);

  const float K0 = scal[0], K1 = scal[1], SP0 = scal[2], SP1 = scal[3];
  const float pb0 = posB[0], pb1 = posB[1];
  const float g10 = ln1g[0], g11 = ln1g[1], b10 = ln1b[0], b11 = ln1b[1];

  float bias_r[4];
#pragma unroll
  for (int g = 0; g < 4; g++) bias_r[g] = biasv[g * 256 + u];
  float Pp0, Pp1;
  {
    float gg = ln2g[u];
    Pp0 = gg * posW[u];
    Pp1 = gg * posW[256 + u];
  }

  // ---- c0 ----
  f32x4 c_r[4];
#pragma unroll
  for (int mt = 0; mt < 4; mt++)
#pragma unroll
    for (int r = 0; r < 4; r++)
      c_r[mt][r] = c0[(size_t)(P0 + pw * 64 + mt * 16 + q * 4 + r) * 256 + u];

  // ---- h0 -> h_stage (all 64 chunks) ----
#pragma unroll
  for (int it = 0; it < 8; it++) {
    int f = tid + it * 512;  // 0..4095
    int ll = f & 63, kc = (f >> 6) & 7, Tl = f >> 9;
    const float* src =
        h0 + (size_t)(P0 + Tl * 16 + (ll & 15)) * 256 + kc * 32 + (ll >> 4) * 8;
    float tf[8];
    *(float4*)&tf[0] = *(const float4*)(src);
    *(float4*)&tf[4] = *(const float4*)(src + 4);
    short8 sv;
#pragma unroll
    for (int j = 0; j < 8; j++) sv[j] = (short)f2bf(tf[j]);
    *(short8*)(h_stage + f * 8) = sv;
  }

  // ---- n01 from lpr ----
  if (tid < 128) {
    float r0 = lpr[(P0 + tid) * 2], r1 = lpr[(P0 + tid) * 2 + 1];
    float d = 0.5f * (r0 - r1);
    float rs = rsqrtf(d * d + 1e-5f);
    n01[tid][0] = d * rs * g10 + b10;
    n01[tid][1] = -d * rs * g11 + b11;
  }
  __syncthreads();

  // ---- x0 = embed(n01) into xh ----
  {
    const int pc = tid >> 2, s4 = tid & 3;
    float n0 = n01[pc][0], n1 = n01[pc][1];
    int Tl = pc >> 4, row = pc & 15;
#pragma unroll
    for (int jj = 0; jj < 16; jj++) {
      int k = s4 * 16 + jj;
      float e = n0 * embW[k * 2] + n1 * embW[k * 2 + 1] + embB[k];
      e = e > 0.f ? e : 0.01f * e;
      xh[(Tl * 2 + (k >> 5)) * 512 + (row + 16 * ((k & 31) >> 3)) * 8 + (k & 7)] =
          f2bf(e);
    }
  }
  __syncthreads();

  for (int st = 0; st < 30; st++) {
    const int par = st & 1, parn = par ^ 1;

    f32x4 acc[4][4];
#pragma unroll
    for (int g = 0; g < 4; g++)
#pragma unroll
      for (int mt = 0; mt < 4; mt++)
        acc[g][mt] = (f32x4){bias_r[g], bias_r[g], bias_r[g], bias_r[g]};

    // ---- x phase (reads xh) ----
#pragma unroll
    for (int kc2 = 0; kc2 < 2; kc2++) {
      short8 ax[4];
#pragma unroll
      for (int mt = 0; mt < 4; mt++)
        ax[mt] = *(const short8*)(xh + ((pw * 4 + mt) * 2 + kc2) * 512 + loff);
#pragma unroll
      for (int g = 0; g < 4; g++) {
        short8 b = *(const short8*)(w_lds + (kc2 * 16 + g * 4 + uw) * 512 + loff);
#pragma unroll
        for (int mt = 0; mt < 4; mt++)
          acc[g][mt] = mfma16(ax[mt], b, acc[g][mt]);
      }
    }
    __syncthreads();  // #1: xh reads done before h_out overlay writes

    // ---- h phase ----
#pragma unroll
    for (int kc = 0; kc < 8; kc++) {
      short8 a[4];
#pragma unroll
      for (int mt = 0; mt < 4; mt++)
        a[mt] = *(const short8*)(h_stage + ((pw * 4 + mt) * 8 + kc) * 512 + loff);
      if (kc < 2) {
#pragma unroll
        for (int g = 0; g < 4; g++) {
          short8 b =
              *(const short8*)(w_lds + ((kc + 2) * 16 + g * 4 + uw) * 512 + loff);
#pragma unroll
          for (int mt = 0; mt < 4; mt++)
            acc[g][mt] = mfma16(a[mt], b, acc[g][mt]);
        }
      } else {
#pragma unroll
        for (int g = 0; g < 4; g++)
#pragma unroll
          for (int mt = 0; mt < 4; mt++)
            acc[g][mt] = mfma16(a[mt], wr[kc - 2][g], acc[g][mt]);
      }
    }

    // ---- cell: c,h update; h_out (xh overlay) + partials ----
#pragma unroll
    for (int mt = 0; mt < 4; mt++) {
      float sh[4], sh2[4], sA[4], sB[4];
#pragma unroll
      for (int r = 0; r < 4; r++) {
        float iv = sigm(acc[0][mt][r]);
        float fv = sigm(acc[1][mt][r]);
        float gv = tanh_(acc[2][mt][r]);
        float ov = sigm(acc[3][mt][r]);
        float cc = fv * c_r[mt][r] + iv * gv;
        c_r[mt][r] = cc;
        float hv = ov * tanh_(cc);
        xh[((pw * 4 + mt) * 2 + (uw >> 1)) * 512 +
           ((q * 4 + r) + 16 * ((uw & 1) * 2 + (li >> 3))) * 8 + (li & 7)] =
            f2bf(hv);
        sh[r] = hv;
        sh2[r] = hv * hv;
        sA[r] = hv * Pp0;
        sB[r] = hv * Pp1;
      }
#pragma unroll
      for (int mask = 1; mask <= 8; mask <<= 1) {
#pragma unroll
        for (int r = 0; r < 4; r++) {
          sh[r] += __shfl_xor(sh[r], mask, 64);
          sh2[r] += __shfl_xor(sh2[r], mask, 64);
          sA[r] += __shfl_xor(sA[r], mask, 64);
          sB[r] += __shfl_xor(sB[r], mask, 64);
        }
      }
      if (li == 0) {
#pragma unroll
        for (int r = 0; r < 4; r++)
          *(f32x4*)(partials + (pw * 64 + mt * 16 + q * 4 + r) * 16 + uw * 4) =
              (f32x4){sh[r], sh2[r], sA[r], sB[r]};
      }
    }
    __syncthreads();  // #2

    // ---- stats combine + store (coalesced); h flush, own slice kept --------
    u64 vown[4];
    if (tid < 128) {
      int pl = tid;
      f32x4 s = *(const f32x4*)(partials + pl * 16);
#pragma unroll
      for (int uu = 1; uu < 4; uu++) {
        f32x4 v = *(const f32x4*)(partials + pl * 16 + uu * 4);
        s.x += v.x;
        s.y += v.y;
        s.z += v.z;
        s.w += v.w;
      }
      // stats[par][pg][ug][pl] (float4) -> u64 pair, contiguous across pl
      u64* sw = (u64*)stats + ((size_t)((par * 64 + pg) * 4 + ug) * 128 + pl) * 2;
      float2 lo2 = make_float2(s.x, s.y), hi2 = make_float2(s.z, s.w);
      st_ag(sw + 0, __builtin_bit_cast(u64, lo2));
      st_ag(sw + 1, __builtin_bit_cast(u64, hi2));
    }
#pragma unroll
    for (int it = 0; it < 4; it++) {
      int f8 = tid + it * 512;  // u64 slot in xh, 0..2047
      int c = f8 >> 7, rr = f8 & 127;
      int Tl = c >> 1, kcl = c & 1;
      u64 v = ((const u64*)xh)[f8];
      vown[it] = v;
      if (st < 29)
        st_ag((u64*)hbuf + (size_t)parn * 524288 +
                  ((size_t)(pg * 8 + Tl) * 8 + ug * 2 + kcl) * 128 + rr,
              v);
    }
    __syncthreads();  // #3: drains all stores before counter bump

    if (tid == 0) {
      __hip_atomic_fetch_add(ctr + pg * 64, 1, __ATOMIC_RELAXED,
                             __HIP_MEMORY_SCOPE_AGENT);
      int target = 4 * (st + 1);
      while (__hip_atomic_load(ctr + pg * 64, __ATOMIC_RELAXED,
                               __HIP_MEMORY_SCOPE_AGENT) < target)
        __builtin_amdgcn_s_sleep(1);
    }
    __syncthreads();

    // ---- batched partner-h loads (issue early, single drain) ----
    u64 hreg[12];
    if (st < 29) {
#pragma unroll
      for (int it = 0; it < 12; it++) {
        int f = tid + it * 512;  // 0..6143
        int pi = f >> 7, rr = f & 127;
        int Tl = pi / 6, j = pi - Tl * 6;
        int kc = j + (j >= 2 * ug ? 2 : 0);
        hreg[it] = ld_ag((const u64*)hbuf + (size_t)parn * 524288 +
                         ((size_t)(pg * 8 + Tl) * 8 + kc) * 128 + rr);
      }
    }

    // ---- rel + out + n01 (stats loads overlap partner-h loads) ----
    if (tid < 128) {
      int pl = tid, pedg = P0 + pl;
      const u64* sb = (const u64*)stats + (size_t)(par * 64 + pg) * 4 * 256;
      float2 a0 = __builtin_bit_cast(float2, ld_ag(sb + (0 * 128 + pl) * 2));
      float2 b0 = __builtin_bit_cast(float2, ld_ag(sb + (0 * 128 + pl) * 2 + 1));
      float2 a1 = __builtin_bit_cast(float2, ld_ag(sb + (1 * 128 + pl) * 2));
      float2 b1 = __builtin_bit_cast(float2, ld_ag(sb + (1 * 128 + pl) * 2 + 1));
      float2 a2 = __builtin_bit_cast(float2, ld_ag(sb + (2 * 128 + pl) * 2));
      float2 b2 = __builtin_bit_cast(float2, ld_ag(sb + (2 * 128 + pl) * 2 + 1));
      float2 a3 = __builtin_bit_cast(float2, ld_ag(sb + (3 * 128 + pl) * 2));
      float2 b3 = __builtin_bit_cast(float2, ld_ag(sb + (3 * 128 + pl) * 2 + 1));
      float S = a0.x + a1.x + a2.x + a3.x;
      float S2 = a0.y + a1.y + a2.y + a3.y;
      float D0 = b0.x + b1.x + b2.x + b3.x;
      float D1 = b0.y + b1.y + b2.y + b3.y;
      float mu = S * (1.0f / 256.0f);
      float var = S2 * (1.0f / 256.0f) - mu * mu;
      float rsig = rsqrtf(var + 1e-5f);
      float rel0 = sigm(rsig * (D0 - mu * SP0) + K0 + pb0);
      float rel1 = sigm(rsig * (D1 - mu * SP1) + K1 + pb1);
      if (ug == 0)
        *(float2*)(out + (size_t)st * 16384 + pedg * 2) =
            make_float2(rel0, rel1);
      float d = 0.5f * (rel0 - rel1);
      float rs = rsqrtf(d * d + 1e-5f);
      n01[pl][0] = d * rs * g10 + b10;
      n01[pl][1] = -d * rs * g11 + b11;
    }
    __syncthreads();  // #4: n01 ready; xh free to overwrite

    if (st < 29) {
      // next x = embed(n01) into xh
      {
        const int pc = tid >> 2, s4 = tid & 3;
        float n0 = n01[pc][0], n1 = n01[pc][1];
        int Tl = pc >> 4, row = pc & 15;
#pragma unroll
        for (int jj = 0; jj < 16; jj++) {
          int k = s4 * 16 + jj;
          float e = n0 * embW[k * 2] + n1 * embW[k * 2 + 1] + embB[k];
          e = e > 0.f ? e : 0.01f * e;
          xh[(Tl * 2 + (k >> 5)) * 512 + (row + 16 * ((k & 31) >> 3)) * 8 +
             (k & 7)] = f2bf(e);
        }
      }
      // h_stage writes: own slice from vown, partner slices from hreg
#pragma unroll
      for (int it = 0; it < 4; it++) {
        int f8 = tid + it * 512;
        int c = f8 >> 7, rr = f8 & 127;
        int Tl = c >> 1, kcl = c & 1;
        ((u64*)h_stage)[(Tl * 8 + ug * 2 + kcl) * 128 + rr] = vown[it];
      }
#pragma unroll
      for (int it = 0; it < 12; it++) {
        int f = tid + it * 512;
        int pi = f >> 7, rr = f & 127;
        int Tl = pi / 6, j = pi - Tl * 6;
        int kc = j + (j >= 2 * ug ? 2 : 0);
        ((u64*)h_stage)[(Tl * 8 + kc) * 128 + rr] = hreg[it];
      }
    }
    __syncthreads();  // #5
  }
}

extern "C" void kernel_launch(void* const* d_in, const int* in_sizes, int n_in,
                              void* d_out, int out_size, void* d_ws,
                              size_t ws_size, hipStream_t stream) {
  (void)in_sizes; (void)n_in; (void)out_size; (void)ws_size;
  const float* lpr  = (const float*)d_in[1];
  const float* h0   = (const float*)d_in[2];
  const float* c0   = (const float*)d_in[3];
  const float* Wih  = (const float*)d_in[4];
  const float* Whh  = (const float*)d_in[5];
  const float* b_ih = (const float*)d_in[6];
  const float* b_hh = (const float*)d_in[7];
  const float* embW = (const float*)d_in[8];
  const float* embB = (const float*)d_in[9];
  const float* ln1g = (const float*)d_in[10];
  const float* ln1b = (const float*)d_in[11];
  const float* posW = (const float*)d_in[12];
  const float* posB = (const float*)d_in[13];
  const float* ln2g = (const float*)d_in[14];
  const float* ln2b = (const float*)d_in[15];

  char* ws = (char*)d_ws;
  unsigned short* ws_w = (unsigned short*)(ws + WS_W);
  unsigned short* hbuf = (unsigned short*)(ws + WS_HBUF);
  float* statsp = (float*)(ws + WS_STATS);
  float* biasv  = (float*)(ws + WS_BIAS);
  float* scal   = (float*)(ws + WS_SCAL);
  int*   ctr    = (int*)(ws + WS_CTR);

  shuffle_weights<<<dim3(160), dim3(256), 0, stream>>>(Wih, Whh, ws_w);
  prologue2<<<dim3(1), dim3(256), 0, stream>>>(b_ih, b_hh, ln2g, ln2b, posW,
                                               biasv, scal, ctr);
  decoder_main<<<dim3(256), dim3(512), 0, stream>>>(
      lpr, h0, c0, embW, embB, ln1g, ln1b, posW, posB, ln2g, ws_w, hbuf,
      statsp, biasv, scal, ctr, (float*)d_out);
}

// Round 7
// 671.217 us; speedup vs baseline: 1.5028x; 1.5028x over previous
//
#include <hip/hip_runtime.h>

// DecoderLSTM R7: unit-partitioned persistent kernel.
// 256 blocks = 64 ped-groups x 4 unit-groups. Block: 128 peds x 64 units.
// Exchange: 16B global_{load,store}_dwordx4 sc0 sc1 via batched asm with
// in-asm s_waitcnt (register-safe, one drain per batch). NO stats exchange:
// LN2 reduction recomputed locally from the full bf16 h each block stages.

typedef float  f32x4  __attribute__((ext_vector_type(4)));
typedef short  short8 __attribute__((ext_vector_type(8)));
typedef __bf16 bf16x8 __attribute__((ext_vector_type(8)));
typedef int    i32x4  __attribute__((ext_vector_type(4)));

#define WS_W     0                     // 640 KB
#define WS_HBUF  (640 * 1024)          // 8 MB: [2][64pg][8Tl][8kc][64] i32x4
#define WS_BIAS  (WS_HBUF + 8388608)   // 4 KB
#define WS_SCAL  (WS_BIAS + 4096)      // 64 B
#define WS_CTR   (WS_SCAL + 64)        // 64 * 256 B

__device__ __forceinline__ unsigned short f2bf(float f) {
  unsigned int u = __float_as_uint(f);
  u += 0x7FFFu + ((u >> 16) & 1u);  // RNE
  return (unsigned short)(u >> 16);
}
__device__ __forceinline__ float bf2f(short s) {
  return __uint_as_float(((unsigned int)(unsigned short)s) << 16);
}
__device__ __forceinline__ float sigm(float x) {
  return __builtin_amdgcn_rcpf(1.0f + __expf(-x));
}
__device__ __forceinline__ float tanh_(float x) {
  float ax = fabsf(x);
  float t = __expf(-2.0f * ax);
  float r = (1.0f - t) * __builtin_amdgcn_rcpf(1.0f + t);
  return x >= 0.0f ? r : -r;
}
__device__ __forceinline__ f32x4 mfma16(short8 a, short8 b, f32x4 c) {
  return __builtin_amdgcn_mfma_f32_16x16x32_bf16(
      __builtin_bit_cast(bf16x8, a), __builtin_bit_cast(bf16x8, b), c, 0, 0, 0);
}
__device__ __forceinline__ void sc_store16(void* p, i32x4 v) {
  asm volatile("global_store_dwordx4 %0, %1, off sc0 sc1" ::"v"(p), "v"(v)
               : "memory");
}
__device__ __forceinline__ void drain_vm() {
  asm volatile("s_waitcnt vmcnt(0)" ::: "memory");
}
// 6 coherent 16B loads, results valid at asm exit (waitcnt inside).
__device__ __forceinline__ void batch_load6(const i32x4* p0, const i32x4* p1,
                                            const i32x4* p2, const i32x4* p3,
                                            const i32x4* p4, const i32x4* p5,
                                            i32x4& r0, i32x4& r1, i32x4& r2,
                                            i32x4& r3, i32x4& r4, i32x4& r5) {
  asm volatile(
      "global_load_dwordx4 %0, %6, off sc0 sc1\n\t"
      "global_load_dwordx4 %1, %7, off sc0 sc1\n\t"
      "global_load_dwordx4 %2, %8, off sc0 sc1\n\t"
      "global_load_dwordx4 %3, %9, off sc0 sc1\n\t"
      "global_load_dwordx4 %4, %10, off sc0 sc1\n\t"
      "global_load_dwordx4 %5, %11, off sc0 sc1\n\t"
      "s_waitcnt vmcnt(0)"
      : "=&v"(r0), "=&v"(r1), "=&v"(r2), "=&v"(r3), "=&v"(r4), "=&v"(r5)
      : "v"(p0), "v"(p1), "v"(p2), "v"(p3), "v"(p4), "v"(p5)
      : "memory");
}

// ---- Prologue 1: weights -> B-frag bf16, flat ((ug*10+kc)*16+g*4+uw)*512 ----
extern "C" __global__ void shuffle_weights(const float* __restrict__ Wih,
                                           const float* __restrict__ Whh,
                                           unsigned short* __restrict__ ws_w) {
  int t = blockIdx.x * 256 + threadIdx.x;  // 0..40959
  if (t >= 40960) return;
  int l = t & 63;
  int x = t >> 6;
  int uw = x & 3;
  int g = (x >> 2) & 3;
  int y = x >> 4;  // ug*10 + kc
  int kc = y % 10;
  int ug = y / 10;
  int row = g * 256 + ug * 64 + uw * 16 + (l & 15);
  unsigned short* dst = ws_w + (size_t)t * 8;
  if (kc < 2) {
    const float* src = Wih + row * 64 + kc * 32 + (l >> 4) * 8;
#pragma unroll
    for (int j = 0; j < 8; j++) dst[j] = f2bf(src[j]);
  } else {
    const float* src = Whh + row * 256 + (kc - 2) * 32 + (l >> 4) * 8;
#pragma unroll
    for (int j = 0; j < 8; j++) dst[j] = f2bf(src[j]);
  }
}

// ---- Prologue 2: bias, scal, zero padded counters ---------------------------
extern "C" __global__ void prologue2(const float* __restrict__ b_ih,
                                     const float* __restrict__ b_hh,
                                     const float* __restrict__ ln2g,
                                     const float* __restrict__ ln2b,
                                     const float* __restrict__ posW,
                                     float* __restrict__ biasv,
                                     float* __restrict__ scal,
                                     int* __restrict__ ctr) {
  int t = threadIdx.x;  // 256
#pragma unroll
  for (int k2 = 0; k2 < 4; k2++) {
    int n = t * 4 + k2;
    biasv[n] = b_ih[n] + b_hh[n];
  }
  if (t < 64) ctr[t * 64] = 0;
  __shared__ float red[256][4];
  float g = ln2g[t], b = ln2b[t], p0 = posW[t], p1 = posW[256 + t];
  red[t][0] = b * p0;
  red[t][1] = b * p1;
  red[t][2] = g * p0;
  red[t][3] = g * p1;
  __syncthreads();
  for (int s = 128; s > 0; s >>= 1) {
    if (t < s) {
#pragma unroll
      for (int v = 0; v < 4; v++) red[t][v] += red[t + s][v];
    }
    __syncthreads();
  }
  if (t == 0) {
#pragma unroll
    for (int v = 0; v < 4; v++) scal[v] = red[0][v];
  }
}

// ---- Main persistent decoder ------------------------------------------------
extern "C" __global__ __launch_bounds__(512, 2) void decoder_main(
    const float* __restrict__ lpr, const float* __restrict__ h0,
    const float* __restrict__ c0, const float* __restrict__ embW,
    const float* __restrict__ embB, const float* __restrict__ ln1g,
    const float* __restrict__ ln1b, const float* __restrict__ posW,
    const float* __restrict__ posB, const float* __restrict__ ln2g,
    const unsigned short* __restrict__ ws_w,
    unsigned short* __restrict__ hbuf,  // [2][64][8][8][64] i32x4
    const float* __restrict__ biasv, const float* __restrict__ scal,
    int* __restrict__ ctr, float* __restrict__ out) {
  __shared__ unsigned short w_lds[4 * 16 * 512];   // 64 KB, kc 0..3
  __shared__ unsigned short h_stage[8 * 8 * 512];  // 64 KB [Tl8][kc8][512]
  __shared__ unsigned short xh[16 * 512];          // 16 KB x-frags / h_out
  __shared__ float ppt[512];                       // [u][2]: g*P0, g*P1
  __shared__ float n01[128][2];

  const int bid = blockIdx.x;
  const int pg = bid >> 2, ug = bid & 3;
  const int tid = threadIdx.x;
  const int w = tid >> 6, l = tid & 63;
  const int uw = w & 3, pw = w >> 2;
  const int q = l >> 4, li = l & 15;
  const int P0 = pg * 128;
  const int loff = l * 8;
  const int u = ug * 64 + uw * 16 + li;

  // ---- weights: LDS part (kc 0..3) ----
  {
    const unsigned short* src = ws_w + (size_t)ug * 81920;
#pragma unroll
    for (int it = 0; it < 8; it++) {
      int f = tid + it * 512;
      *(short8*)(w_lds + f * 8) = *(const short8*)(src + f * 8);
    }
  }
  // ---- weights: register part (kc 4..9) ----
  short8 wr[6][4];
#pragma unroll
  for (int kk = 0; kk < 6; kk++)
#pragma unroll
    for (int g = 0; g < 4; g++)
      wr[kk][g] = *(const short8*)(ws_w + (size_t)ug * 81920 +
                                   ((kk + 4) * 16 + g * 4 + uw) * 512 + loff);

  const float K0 = scal[0], K1 = scal[1], SP0 = scal[2], SP1 = scal[3];
  const float pb0 = posB[0], pb1 = posB[1];
  const float g10 = ln1g[0], g11 = ln1g[1], b10 = ln1b[0], b11 = ln1b[1];

  float bias_r[4];
#pragma unroll
  for (int g = 0; g < 4; g++) bias_r[g] = biasv[g * 256 + u];

  // ---- ppt table: ln2g[u]*posW[r][u], interleaved [u][2] ----
  {
    int uu = tid & 255, r = tid >> 8;  // tid<512 covers r in {0,1}
    ppt[uu * 2 + r] = ln2g[uu] * posW[r * 256 + uu];
  }

  // ---- c0 ----
  f32x4 c_r[4];
#pragma unroll
  for (int mt = 0; mt < 4; mt++)
#pragma unroll
    for (int r = 0; r < 4; r++)
      c_r[mt][r] = c0[(size_t)(P0 + pw * 64 + mt * 16 + q * 4 + r) * 256 + u];

  // ---- h0 -> h_stage (all 64 chunks) ----
#pragma unroll
  for (int it = 0; it < 8; it++) {
    int f = tid + it * 512;  // 0..4095
    int ll = f & 63, kc = (f >> 6) & 7, Tl = f >> 9;
    const float* src =
        h0 + (size_t)(P0 + Tl * 16 + (ll & 15)) * 256 + kc * 32 + (ll >> 4) * 8;
    float tf[8];
    *(float4*)&tf[0] = *(const float4*)(src);
    *(float4*)&tf[4] = *(const float4*)(src + 4);
    short8 sv;
#pragma unroll
    for (int j = 0; j < 8; j++) sv[j] = (short)f2bf(tf[j]);
    *(short8*)(h_stage + f * 8) = sv;
  }

  // ---- n01 from lpr ----
  if (tid < 128) {
    float r0 = lpr[(P0 + tid) * 2], r1 = lpr[(P0 + tid) * 2 + 1];
    float d = 0.5f * (r0 - r1);
    float rs = rsqrtf(d * d + 1e-5f);
    n01[tid][0] = d * rs * g10 + b10;
    n01[tid][1] = -d * rs * g11 + b11;
  }
  __syncthreads();

  // ---- x0 = embed(n01) into xh ----
  {
    const int pc = tid >> 2, s4 = tid & 3;
    float n0 = n01[pc][0], n1 = n01[pc][1];
    int Tl = pc >> 4, row = pc & 15;
#pragma unroll
    for (int jj = 0; jj < 16; jj++) {
      int k = s4 * 16 + jj;
      float e = n0 * embW[k * 2] + n1 * embW[k * 2 + 1] + embB[k];
      e = e > 0.f ? e : 0.01f * e;
      xh[(Tl * 2 + (k >> 5)) * 512 + (row + 16 * ((k & 31) >> 3)) * 8 + (k & 7)] =
          f2bf(e);
    }
  }
  __syncthreads();

  i32x4* hb4 = (i32x4*)hbuf;

  for (int st = 0; st < 30; st++) {
    const size_t pbase = (size_t)(st & 1) * 262144;  // parity stride (i32x4)

    f32x4 acc[4][4];
#pragma unroll
    for (int g = 0; g < 4; g++)
#pragma unroll
      for (int mt = 0; mt < 4; mt++)
        acc[g][mt] = (f32x4){bias_r[g], bias_r[g], bias_r[g], bias_r[g]};

    // ---- x phase (reads xh) ----
#pragma unroll
    for (int kc2 = 0; kc2 < 2; kc2++) {
      short8 ax[4];
#pragma unroll
      for (int mt = 0; mt < 4; mt++)
        ax[mt] = *(const short8*)(xh + ((pw * 4 + mt) * 2 + kc2) * 512 + loff);
#pragma unroll
      for (int g = 0; g < 4; g++) {
        short8 b = *(const short8*)(w_lds + (kc2 * 16 + g * 4 + uw) * 512 + loff);
#pragma unroll
        for (int mt = 0; mt < 4; mt++)
          acc[g][mt] = mfma16(ax[mt], b, acc[g][mt]);
      }
    }
    // ---- h phase ----
#pragma unroll
    for (int kc = 0; kc < 8; kc++) {
      short8 a[4];
#pragma unroll
      for (int mt = 0; mt < 4; mt++)
        a[mt] = *(const short8*)(h_stage + ((pw * 4 + mt) * 8 + kc) * 512 + loff);
      if (kc < 2) {
#pragma unroll
        for (int g = 0; g < 4; g++) {
          short8 b =
              *(const short8*)(w_lds + ((kc + 2) * 16 + g * 4 + uw) * 512 + loff);
#pragma unroll
          for (int mt = 0; mt < 4; mt++)
            acc[g][mt] = mfma16(a[mt], b, acc[g][mt]);
        }
      } else {
#pragma unroll
        for (int g = 0; g < 4; g++)
#pragma unroll
          for (int mt = 0; mt < 4; mt++)
            acc[g][mt] = mfma16(a[mt], wr[kc - 2][g], acc[g][mt]);
      }
    }
    __syncthreads();  // #1: all xh / h_stage reads of this step done

    // ---- cell: c,h update; own h frags -> xh overlay ----
#pragma unroll
    for (int mt = 0; mt < 4; mt++) {
#pragma unroll
      for (int r = 0; r < 4; r++) {
        float iv = sigm(acc[0][mt][r]);
        float fv = sigm(acc[1][mt][r]);
        float gv = tanh_(acc[2][mt][r]);
        float ov = sigm(acc[3][mt][r]);
        float cc = fv * c_r[mt][r] + iv * gv;
        c_r[mt][r] = cc;
        float hv = ov * tanh_(cc);
        xh[((pw * 4 + mt) * 2 + (uw >> 1)) * 512 +
           ((q * 4 + r) + 16 * ((uw & 1) * 2 + (li >> 3))) * 8 + (li & 7)] =
            f2bf(hv);
      }
    }
    __syncthreads();  // #2: own h frags complete in xh

    // ---- store own slice (16B coherent), capture vown ----
    i32x4 vown[2];
    {
      const i32x4* xh4 = (const i32x4*)xh;
#pragma unroll
      for (int it = 0; it < 2; it++) {
        int f = tid + it * 512;  // 0..1023
        int s = f & 63, c = f >> 6, Tl = c >> 1, kcl = c & 1;
        vown[it] = xh4[f];
        sc_store16(hb4 + pbase + (((size_t)(pg * 8 + Tl)) * 8 + 2 * ug + kcl) * 64 + s,
                   vown[it]);
      }
      drain_vm();
    }
    __syncthreads();  // #3: all waves' stores drained

    if (tid == 0) {
      __hip_atomic_fetch_add(ctr + pg * 64, 1, __ATOMIC_RELAXED,
                             __HIP_MEMORY_SCOPE_AGENT);
      int target = 4 * (st + 1);
      while (__hip_atomic_load(ctr + pg * 64, __ATOMIC_RELAXED,
                               __HIP_MEMORY_SCOPE_AGENT) < target)
        __builtin_amdgcn_s_sleep(1);
    }
    __syncthreads();  // #4: partners' h visible

    // ---- batched partner loads -> h_stage; own slice from vown ----
    {
      const i32x4* ps[6];
      int Tls[6], kcs[6], ss[6];
#pragma unroll
      for (int it = 0; it < 6; it++) {
        int f = tid + it * 512;  // 0..3071
        int s = f & 63, x = f >> 6;  // 0..47
        int Tl = x / 6, j = x - Tl * 6;
        int kc = j + (j >= 2 * ug ? 2 : 0);
        Tls[it] = Tl; kcs[it] = kc; ss[it] = s;
        ps[it] = hb4 + pbase + (((size_t)(pg * 8 + Tl)) * 8 + kc) * 64 + s;
      }
      i32x4 r0, r1, r2, r3, r4, r5;
      batch_load6(ps[0], ps[1], ps[2], ps[3], ps[4], ps[5], r0, r1, r2, r3, r4,
                  r5);
      i32x4* hs4 = (i32x4*)h_stage;
      hs4[(Tls[0] * 8 + kcs[0]) * 64 + ss[0]] = r0;
      hs4[(Tls[1] * 8 + kcs[1]) * 64 + ss[1]] = r1;
      hs4[(Tls[2] * 8 + kcs[2]) * 64 + ss[2]] = r2;
      hs4[(Tls[3] * 8 + kcs[3]) * 64 + ss[3]] = r3;
      hs4[(Tls[4] * 8 + kcs[4]) * 64 + ss[4]] = r4;
      hs4[(Tls[5] * 8 + kcs[5]) * 64 + ss[5]] = r5;
#pragma unroll
      for (int it = 0; it < 2; it++) {
        int f = tid + it * 512;
        int s = f & 63, c = f >> 6, Tl = c >> 1, kcl = c & 1;
        hs4[(Tl * 8 + 2 * ug + kcl) * 64 + s] = vown[it];
      }
    }
    __syncthreads();  // #5: h_stage = h_st (full)

    // ---- local LN2 reduce (4 threads/ped over bf16 h) + rel + n01 ----
    {
      const int pl = tid >> 2, part = tid & 3;
      const int Tl = pl >> 4, row = pl & 15;
      float S = 0.f, S2 = 0.f, D0 = 0.f, D1 = 0.f;
#pragma unroll
      for (int kk = 0; kk < 2; kk++) {
        int kcx = part * 2 + kk;
#pragma unroll
        for (int sub = 0; sub < 4; sub++) {
          short8 h8 = *(const short8*)(h_stage + (Tl * 8 + kcx) * 512 +
                                       (row + 16 * sub) * 8);
          const float4* pp = (const float4*)(ppt + (kcx * 32 + sub * 8) * 2);
#pragma unroll
          for (int k4 = 0; k4 < 4; k4++) {
            float4 pv = pp[k4];
            float ha = bf2f(h8[2 * k4]);
            float hb = bf2f(h8[2 * k4 + 1]);
            S += ha + hb;
            S2 += ha * ha + hb * hb;
            D0 += ha * pv.x + hb * pv.z;
            D1 += ha * pv.y + hb * pv.w;
          }
        }
      }
      S += __shfl_xor(S, 1, 64);  S += __shfl_xor(S, 2, 64);
      S2 += __shfl_xor(S2, 1, 64); S2 += __shfl_xor(S2, 2, 64);
      D0 += __shfl_xor(D0, 1, 64); D0 += __shfl_xor(D0, 2, 64);
      D1 += __shfl_xor(D1, 1, 64); D1 += __shfl_xor(D1, 2, 64);
      if (part == 0) {
        float mu = S * (1.0f / 256.0f);
        float var = S2 * (1.0f / 256.0f) - mu * mu;
        float rsig = rsqrtf(var + 1e-5f);
        float rel0 = sigm(rsig * (D0 - mu * SP0) + K0 + pb0);
        float rel1 = sigm(rsig * (D1 - mu * SP1) + K1 + pb1);
        if (ug == 0)
          *(float2*)(out + (size_t)st * 16384 + (P0 + pl) * 2) =
              make_float2(rel0, rel1);
        float d = 0.5f * (rel0 - rel1);
        float rs = rsqrtf(d * d + 1e-5f);
        n01[pl][0] = d * rs * g10 + b10;
        n01[pl][1] = -d * rs * g11 + b11;
      }
    }
    __syncthreads();  // #6: n01 ready

    if (st < 29) {
      // next x = embed(n01) into xh
      const int pc = tid >> 2, s4 = tid & 3;
      float n0 = n01[pc][0], n1 = n01[pc][1];
      int Tl = pc >> 4, row = pc & 15;
#pragma unroll
      for (int jj = 0; jj < 16; jj++) {
        int k = s4 * 16 + jj;
        float e = n0 * embW[k * 2] + n1 * embW[k * 2 + 1] + embB[k];
        e = e > 0.f ? e : 0.01f * e;
        xh[(Tl * 2 + (k >> 5)) * 512 + (row + 16 * ((k & 31) >> 3)) * 8 +
           (k & 7)] = f2bf(e);
      }
    }
    __syncthreads();  // #7: xh ready for next step
  }
}

extern "C" void kernel_launch(void* const* d_in, const int* in_sizes, int n_in,
                              void* d_out, int out_size, void* d_ws,
                              size_t ws_size, hipStream_t stream) {
  (void)in_sizes; (void)n_in; (void)out_size; (void)ws_size;
  const float* lpr  = (const float*)d_in[1];
  const float* h0   = (const float*)d_in[2];
  const float* c0   = (const float*)d_in[3];
  const float* Wih  = (const float*)d_in[4];
  const float* Whh  = (const float*)d_in[5];
  const float* b_ih = (const float*)d_in[6];
  const float* b_hh = (const float*)d_in[7];
  const float* embW = (const float*)d_in[8];
  const float* embB = (const float*)d_in[9];
  const float* ln1g = (const float*)d_in[10];
  const float* ln1b = (const float*)d_in[11];
  const float* posW = (const float*)d_in[12];
  const float* posB = (const float*)d_in[13];
  const float* ln2g = (const float*)d_in[14];
  const float* ln2b = (const float*)d_in[15];

  char* ws = (char*)d_ws;
  unsigned short* ws_w = (unsigned short*)(ws + WS_W);
  unsigned short* hbuf = (unsigned short*)(ws + WS_HBUF);
  float* biasv  = (float*)(ws + WS_BIAS);
  float* scal   = (float*)(ws + WS_SCAL);
  int*   ctr    = (int*)(ws + WS_CTR);

  shuffle_weights<<<dim3(160), dim3(256), 0, stream>>>(Wih, Whh, ws_w);
  prologue2<<<dim3(1), dim3(256), 0, stream>>>(b_ih, b_hh, ln2g, ln2b, posW,
                                               biasv, scal, ctr);
  decoder_main<<<dim3(256), dim3(512), 0, stream>>>(
      lpr, h0, c0, embW, embB, ln1g, ln1b, posW, posB, ln2g, ws_w, hbuf,
      biasv, scal, ctr, (float*)d_out);
}